// Round 9
// baseline (750.508 us; speedup 1.0000x reference)
//
#include <hip/hip_runtime.h>

#define B   64
#define K   512
#define C   4
#define NL  5
#define BK  (B*K)

typedef _Float16 half_t;
typedef _Float16 half8 __attribute__((ext_vector_type(8)));
typedef float    f4    __attribute__((ext_vector_type(4)));

// ---------------------------------------------------------------------------
// Batch-scoped generation barrier: 4 blocks per batch. bar[b] is a cumulative
// arrival counter (memset to 0 each launch); barrier #gen waits for 4*gen.
// Device-scope atomics + __threadfence give release/acquire across XCDs.
// ---------------------------------------------------------------------------
__device__ __forceinline__ void batch_barrier(unsigned* __restrict__ bar,
                                              int b, unsigned gen) {
    __syncthreads();
    __threadfence();                      // release: flush stores/atomics
    if (threadIdx.x == 0) {
        atomicAdd(&bar[b], 1u);
        while (atomicAdd(&bar[b], 0u) < 4u * gen)
            __builtin_amdgcn_s_sleep(2);
    }
    __syncthreads();
    __threadfence();                      // acquire: invalidate stale caches
}

// ---------------------------------------------------------------------------
// Per-layer tail for this block's 128 (b,k) elements (k == own row range):
// mu/ula, ar/dl mix, CReLU, rc recombine, power correction. Writes the layer
// output slice, the block-local v (LDS), and global xsq (unless last layer).
// ---------------------------------------------------------------------------
__device__ __forceinline__ void layer_tail(
    int l, int b, int rc, int tid,
    const float* __restrict__ ul_l, const float2* __restrict__ vt_l,
    float2* __restrict__ v_l, const float* __restrict__ mp,
    const float* __restrict__ ar_re, const float* __restrict__ ar_im,
    const float* __restrict__ dl_re, const float* __restrict__ dl_im,
    const float* __restrict__ rc_re, const float* __restrict__ rc_im,
    float* __restrict__ xsq_g, float* __restrict__ out, bool write_xsq)
{
    if (tid < 128) {
        int k  = rc * 128 + tid;
        int bk = b * K + k;
        float  u  = ul_l[bk];
        float2 vt = vt_l[tid];
        float  p  = mp[bk];
        float avt = sqrtf(vt.x * vt.x + vt.y * vt.y);
        float mu  = fmaxf(avt / sqrtf(p) - u, 0.f);
        float inv = 1.f / (u + mu);
        float ax = 0.f, ay = 0.f;
#pragma unroll
        for (int cc = 0; cc < C; ++cc) {
            float gre = ar_re[cc] * inv + dl_re[cc];
            float gim = ar_im[cc] * inv + dl_im[cc];
            float zre = fmaxf(vt.x * gre - vt.y * gim, 0.f);
            float zim = fmaxf(vt.x * gim + vt.y * gre, 0.f);
            ax += zre * rc_re[cc] - zim * rc_im[cc];
            ay += zre * rc_im[cc] + zim * rc_re[cc];
        }
        float n2   = ax * ax + ay * ay;
        float corr = fminf(sqrtf(p / fmaxf(p, n2)), 1.f);
        ax *= corr; ay *= corr;
        v_l[tid] = make_float2(ax, ay);
        ((float2*)out)[(size_t)l * BK + bk] = make_float2(ax, ay);
        if (write_xsq) xsq_g[bk] = ax * ax + ay * ay;
    }
}

// ---------------------------------------------------------------------------
// Persistent mono-kernel. 256 blocks x 512 threads (1 block/CU, co-resident).
// Block (b, rc) owns rows rc*128..+128 of batch b; wave w owns 16 rows,
// lane owns 8 consecutive cols. |H|^2 rows live in REGISTERS (half8 x16 =
// 64 VGPR) for all 5 layers — habs never touches global memory.
// Per layer: cov row-dot + u/w algebra (real-w simplification) -> vtilde
// (LDS), tmv partial from registers -> 8-wave LDS combine -> atomicAdd into
// dense ul[l]; batch barrier; tail; batch barrier.
// ---------------------------------------------------------------------------
__global__ __launch_bounds__(512, 2) void k_mono(
    const float* __restrict__ hre, const float* __restrict__ him,
    const float* __restrict__ noise, const float* __restrict__ mp,
    const float* __restrict__ vre, const float* __restrict__ vim,
    const float* __restrict__ ar_re, const float* __restrict__ ar_im,
    const float* __restrict__ dl_re, const float* __restrict__ dl_im,
    const float* __restrict__ rc_re, const float* __restrict__ rc_im,
    float* __restrict__ xsq_g, float* __restrict__ ul,
    unsigned* __restrict__ bar, float* __restrict__ out)
{
    const int tid  = threadIdx.x;
    const int lane = tid & 63;
    const int wv   = tid >> 6;            // 0..7
    const int b    = blockIdx.x >> 2;
    const int rc   = blockIdx.x & 3;
    const int j0   = rc * 128 + wv * 16;

    __shared__ float  part[8 * 512];      // 16 KB, column-interleaved
    __shared__ float2 vt_l[128];
    __shared__ float2 v_l[128];
    __shared__ float  d2_l[128];

    half8 hreg[16];                       // this wave's 16 rows, fp16

    // layer-1 xs fragment = |v_in|^2 for cols lane*8..+8
    const f4* vr4 = (const f4*)(vre + (size_t)b * K + lane * 8);
    const f4* vi4 = (const f4*)(vim + (size_t)b * K + lane * 8);
    f4 va0 = vr4[0], va1 = vr4[1], wa0 = vi4[0], wa1 = vi4[1];
    float xs[8];
    xs[0] = va0.x * va0.x + wa0.x * wa0.x;
    xs[1] = va0.y * va0.y + wa0.y * wa0.y;
    xs[2] = va0.z * va0.z + wa0.z * wa0.z;
    xs[3] = va0.w * va0.w + wa0.w * wa0.w;
    xs[4] = va1.x * va1.x + wa1.x * wa1.x;
    xs[5] = va1.y * va1.y + wa1.y * wa1.y;
    xs[6] = va1.z * va1.z + wa1.z * wa1.z;
    xs[7] = va1.w * va1.w + wa1.w * wa1.w;

    // ---- load + layer-1 phase A (fp32 precision on layer 1) ----
    float acc8[8] = {0.f, 0.f, 0.f, 0.f, 0.f, 0.f, 0.f, 0.f};
#pragma unroll
    for (int r = 0; r < 16; ++r) {
        const int j  = j0 + r;
        const int lr = wv * 16 + r;
        const size_t ro = ((size_t)b * K + j) * K + (size_t)lane * 8;
        const f4* hr = (const f4*)(hre + ro);
        const f4* hi = (const f4*)(him + ro);
        f4 r0 = __builtin_nontemporal_load(hr);
        f4 r1 = __builtin_nontemporal_load(hr + 1);
        f4 i0 = __builtin_nontemporal_load(hi);
        f4 i1 = __builtin_nontemporal_load(hi + 1);
        float s[8];
        s[0] = r0.x * r0.x + i0.x * i0.x;
        s[1] = r0.y * r0.y + i0.y * i0.y;
        s[2] = r0.z * r0.z + i0.z * i0.z;
        s[3] = r0.w * r0.w + i0.w * i0.w;
        s[4] = r1.x * r1.x + i1.x * i1.x;
        s[5] = r1.y * r1.y + i1.y * i1.y;
        s[6] = r1.z * r1.z + i1.z * i1.z;
        s[7] = r1.w * r1.w + i1.w * i1.w;

        float d2   = __shfl(s[j & 7],  j >> 3, 64);   // |H_jj|^2 fp32
        float xsqj = __shfl(xs[j & 7], j >> 3, 64);

        float dot = s[0] * xs[0] + s[1] * xs[1] + s[2] * xs[2] + s[3] * xs[3] +
                    s[4] * xs[4] + s[5] * xs[5] + s[6] * xs[6] + s[7] * xs[7];
#pragma unroll
        for (int o = 32; o; o >>= 1) dot += __shfl_xor(dot, o, 64);

        float ulv = 0.f;
        if (lane == 0) {
            const int bj = b * K + j;
            float cov = dot + noise[bj];
            float A   = d2 * xsqj;
            float w   = cov / (cov - A);
            float sc  = d2 * w / cov;
            vt_l[lr] = make_float2(sc * vre[bj], sc * vim[bj]);
            d2_l[lr] = d2;
            ulv = A * w / (cov * cov);
        }
        ulv = __shfl(ulv, 0, 64);
#pragma unroll
        for (int q = 0; q < 8; ++q) acc8[q] += s[q] * ulv;

        half8 hh;
#pragma unroll
        for (int q = 0; q < 8; ++q) hh[q] = (_Float16)s[q];
        hreg[r] = hh;
    }

    // combine 8 wave-partials (conflict-free interleaved layout) + atomic
#pragma unroll
    for (int q = 0; q < 8; ++q) part[wv * 512 + q * 64 + lane] = acc8[q];
    __syncthreads();
    {
        const int c   = tid;
        const int off = ((c & 7) << 6) + (c >> 3);
        float t = 0.f;
#pragma unroll
        for (int w = 0; w < 8; ++w) t += part[w * 512 + off];
        atomicAdd(&ul[b * K + c], t);
    }
    batch_barrier(bar, b, 1);
    layer_tail(0, b, rc, tid, ul, vt_l, v_l, mp,
               ar_re, ar_im, dl_re, dl_im, rc_re, rc_im,
               xsq_g, out, true);
    batch_barrier(bar, b, 2);

    // ---- layers 2..5: pure register compute ----
#pragma unroll 1
    for (int l = 1; l < NL; ++l) {
        const f4* xq = (const f4*)(xsq_g + (size_t)b * K + lane * 8);
        f4 xa = xq[0], xb = xq[1];
        float xs2[8] = {xa.x, xa.y, xa.z, xa.w, xb.x, xb.y, xb.z, xb.w};
        float acc[8] = {0.f, 0.f, 0.f, 0.f, 0.f, 0.f, 0.f, 0.f};
#pragma unroll
        for (int r = 0; r < 16; ++r) {
            const int j  = j0 + r;
            const int lr = wv * 16 + r;
            half8 hh = hreg[r];
            float s[8];
#pragma unroll
            for (int q = 0; q < 8; ++q) s[q] = (float)hh[q];
            float dot = s[0] * xs2[0] + s[1] * xs2[1] + s[2] * xs2[2] +
                        s[3] * xs2[3] + s[4] * xs2[4] + s[5] * xs2[5] +
                        s[6] * xs2[6] + s[7] * xs2[7];
#pragma unroll
            for (int o = 32; o; o >>= 1) dot += __shfl_xor(dot, o, 64);
            float ulv = 0.f;
            if (lane == 0) {
                const int bj = b * K + j;
                float d2  = d2_l[lr];
                float cov = dot + noise[bj];
                float A   = d2 * xsq_g[bj];
                float w   = cov / (cov - A);
                float sc  = d2 * w / cov;
                float2 vv = v_l[lr];
                vt_l[lr] = make_float2(sc * vv.x, sc * vv.y);
                ulv = A * w / (cov * cov);
            }
            ulv = __shfl(ulv, 0, 64);
#pragma unroll
            for (int q = 0; q < 8; ++q) acc[q] += s[q] * ulv;
        }

#pragma unroll
        for (int q = 0; q < 8; ++q) part[wv * 512 + q * 64 + lane] = acc[q];
        __syncthreads();
        {
            const int c   = tid;
            const int off = ((c & 7) << 6) + (c >> 3);
            float t = 0.f;
#pragma unroll
            for (int w = 0; w < 8; ++w) t += part[w * 512 + off];
            atomicAdd(&ul[(size_t)l * BK + b * K + c], t);
        }
        batch_barrier(bar, b, 2 * l + 1);
        layer_tail(l, b, rc, tid, ul + (size_t)l * BK, vt_l, v_l, mp,
                   ar_re, ar_im, dl_re, dl_im, rc_re, rc_im,
                   xsq_g, out, l < NL - 1);
        if (l < NL - 1) batch_barrier(bar, b, 2 * l + 2);
    }
}

// ---------------------------------------------------------------------------
extern "C" void kernel_launch(void* const* d_in, const int* in_sizes, int n_in,
                              void* d_out, int out_size, void* d_ws, size_t ws_size,
                              hipStream_t stream) {
    const float* hre   = (const float*)d_in[0];
    const float* him   = (const float*)d_in[1];
    const float* noise = (const float*)d_in[2];
    const float* mp    = (const float*)d_in[3];
    const float* vre   = (const float*)d_in[4];
    const float* vim   = (const float*)d_in[5];
    const float* ar_re = (const float*)d_in[6];
    const float* ar_im = (const float*)d_in[7];
    const float* dl_re = (const float*)d_in[8];
    const float* dl_im = (const float*)d_in[9];
    const float* rc_re = (const float*)d_in[10];
    const float* rc_im = (const float*)d_in[11];
    float* out = (float*)d_out;

    char*     ws    = (char*)d_ws;
    float*    xsq_g = (float*)ws;                                   // 128 KB
    float*    ul    = (float*)(ws + (size_t)BK * 4);                // 640 KB
    unsigned* bar   = (unsigned*)(ws + (size_t)BK * 4 + (size_t)NL * BK * 4);

    // zero ul (atomic accumulators) + bar (barrier counters) in one memset
    hipMemsetAsync(ul, 0, (size_t)NL * BK * 4 + B * sizeof(unsigned), stream);

    // 256 blocks x 512 threads = 1 block/CU, co-resident by construction
    k_mono<<<B * 4, 512, 0, stream>>>(hre, him, noise, mp, vre, vim,
                                      ar_re, ar_im, dl_re, dl_im, rc_re, rc_im,
                                      xsq_g, ul, bar, out);
}